// Round 7
// baseline (153.977 us; speedup 1.0000x reference)
//
#include <hip/hip_runtime.h>
#include <hip/hip_bf16.h>

#define HH 24
#define WW 8
#define HWSZ 192
#define CC 128
#define EPSV 1e-5f

#define M1LD 200   // M1 [24][M1LD] bf16
#define M2LD 28    // M2 [192][M2LD] bf16

typedef __attribute__((ext_vector_type(8))) short bf16x8;
typedef __attribute__((ext_vector_type(4))) float f32x4;

__device__ __forceinline__ float sigmoidf_(float x) { return 1.0f / (1.0f + expf(-x)); }

__device__ __forceinline__ unsigned short f2bf(float f) {
    unsigned int u = __float_as_uint(f);
    unsigned int r = (u + 0x7fffu + ((u >> 16) & 1u)) >> 16;
    return (unsigned short)r;
}
__device__ __forceinline__ float bf2f(unsigned short s) {
    return __uint_as_float((unsigned int)s << 16);
}

// ---------------- Kernel 1a: CBAM stats (phases 1-5), 64 blocks x 512 ----------------
__global__ __launch_bounds__(512) void cbam_stats(
    const float* __restrict__ prob, const float* __restrict__ gal,
    const float* __restrict__ se_w1, const float* __restrict__ se_w2,
    const float* __restrict__ sa_w, const float* __restrict__ sa_b,
    float* __restrict__ ca_out, float* __restrict__ sa_out)
{
    __shared__ float mxs[CC], avs[CC], hid[16], cas[CC];
    __shared__ float smx2[2 * HWSZ], sav2[2 * HWSZ];
    __shared__ float wbuf[2 * 49 * 49];

    int n = blockIdx.x;
    const float* x = (n < 32) ? prob + (size_t)n * CC * HWSZ : gal + (size_t)(n - 32) * CC * HWSZ;

    int tid = threadIdx.x, l = tid & 63, w = tid >> 6;

    for (int i = tid; i < 2 * 49 * 49; i += 512) wbuf[i] = sa_w[i];

    // phase 1: per-channel max/mean over 192 spatial (8 waves x 16 channels)
    for (int i = 0; i < 16; ++i) {
        int c = w * 16 + i;
        const float* row = x + c * HWSZ;
        float a = row[l], b = row[l + 64], d = row[l + 128];
        float mv = fmaxf(a, fmaxf(b, d));
        float sv = a + b + d;
        #pragma unroll
        for (int m = 1; m < 64; m <<= 1) {
            mv = fmaxf(mv, __shfl_xor(mv, m));
            sv += __shfl_xor(sv, m);
        }
        if (l == 0) { mxs[c] = mv; avs[c] = sv * (1.0f / HWSZ); }
    }
    __syncthreads();

    // phase 2: hidden = relu(v @ W1^T); 16 outputs x 16 lanes x 8 channels
    if (tid < 256) {
        int j = tid >> 4, chunk = tid & 15;
        const float* v = (j < 8) ? mxs : avs;
        const float* wrow = se_w1 + (j & 7) * CC + chunk * 8;
        const float* vv = v + chunk * 8;
        float acc = 0.f;
        #pragma unroll
        for (int k = 0; k < 8; ++k) acc += vv[k] * wrow[k];
        #pragma unroll
        for (int m = 1; m < 16; m <<= 1) acc += __shfl_xor(acc, m);
        if (chunk == 0) hid[j] = fmaxf(acc, 0.f);
    }
    __syncthreads();

    // phase 3: ca[c]
    if (tid < CC) {
        float acc = 0.f;
        #pragma unroll
        for (int j = 0; j < 8; ++j) acc += (hid[j] + hid[8 + j]) * se_w2[tid * 8 + j];
        cas[tid] = sigmoidf_(acc);
        ca_out[n * CC + tid] = cas[tid];
    }
    __syncthreads();

    // phase 4: spatial max/sum over channels of out = x*ca (2 half-channel passes)
    if (tid < 2 * HWSZ) {
        int s = tid >> 1, half = tid & 1;
        int c0 = half * 64;
        float mv = -INFINITY, sv = 0.f;
        #pragma unroll 4
        for (int k = 0; k < 64; ++k) {
            float v = x[(c0 + k) * HWSZ + s] * cas[c0 + k];
            mv = fmaxf(mv, v); sv += v;
        }
        smx2[half * HWSZ + s] = mv; sav2[half * HWSZ + s] = sv;
    }
    __syncthreads();

    // phase 5: 49x49 conv (pad 24 = all-pairs) + sigmoid -> sa_out
    if (tid < HWSZ) {
        int y = tid >> 3, xx = tid & 7;
        float acc = sa_b[0];
        for (int iy = 0; iy < HH; ++iy) {
            int wy = iy - y + 24;
            const float* w0 = wbuf + wy * 49;
            const float* w1 = wbuf + 2401 + wy * 49;
            #pragma unroll
            for (int ix = 0; ix < WW; ++ix) {
                int wx = ix - xx + 24;
                int sp = iy * 8 + ix;
                float s0 = fmaxf(smx2[sp], smx2[HWSZ + sp]);
                float s1 = (sav2[sp] + sav2[HWSZ + sp]) * (1.0f / CC);
                acc += s0 * w0[wx] + s1 * w1[wx];
            }
        }
        sa_out[n * HWSZ + tid] = sigmoidf_(acc);
    }
}

// ---------------- Kernel 1b: CBAM apply + transpose, 768 blocks x 256 ----------------
// out[s][c] = x[c][s] * (1 + ca[c]*sa[s]) as bf16
// FIX vs R5: c = tid>>1 covers all 128 channels (was tid>>2 -> only 0..63,
// leaving T[.][64..127] uninitialized -> NaN).
__global__ __launch_bounds__(256) void cbam_apply(
    const float* __restrict__ prob, const float* __restrict__ gal,
    const float* __restrict__ ca_buf, const float* __restrict__ sa_buf,
    __hip_bfloat16* __restrict__ pf_t, __hip_bfloat16* __restrict__ gf_t)
{
    __shared__ unsigned short T[16][136];   // [s_local][c], padded
    __shared__ float sash[16];

    int n = blockIdx.x / 12;
    int s0 = (blockIdx.x % 12) * 16;
    const float* x = (n < 32) ? prob + (size_t)n * CC * HWSZ : gal + (size_t)(n - 32) * CC * HWSZ;
    __hip_bfloat16* dst = (n < 32) ? pf_t + (size_t)n * HWSZ * CC : gf_t + (size_t)(n - 32) * HWSZ * CC;

    int tid = threadIdx.x;
    if (tid < 16) sash[tid] = sa_buf[n * HWSZ + s0 + tid];
    __syncthreads();

    int c = tid >> 1, half = tid & 1;           // c: 0..127, half: 0..1
    float ca = ca_buf[n * CC + c];
    const float* xp = x + c * HWSZ + s0 + half * 8;
    float4 va = *(const float4*)xp;
    float4 vb = *(const float4*)(xp + 4);
    int r0 = half * 8;
    T[r0 + 0][c] = f2bf(va.x * (1.f + ca * sash[r0 + 0]));
    T[r0 + 1][c] = f2bf(va.y * (1.f + ca * sash[r0 + 1]));
    T[r0 + 2][c] = f2bf(va.z * (1.f + ca * sash[r0 + 2]));
    T[r0 + 3][c] = f2bf(va.w * (1.f + ca * sash[r0 + 3]));
    T[r0 + 4][c] = f2bf(vb.x * (1.f + ca * sash[r0 + 4]));
    T[r0 + 5][c] = f2bf(vb.y * (1.f + ca * sash[r0 + 5]));
    T[r0 + 6][c] = f2bf(vb.z * (1.f + ca * sash[r0 + 6]));
    T[r0 + 7][c] = f2bf(vb.w * (1.f + ca * sash[r0 + 7]));
    __syncthreads();

    // write out: 16 threads per row, 8 channels (16B) each
    int s_l = tid >> 4, c8 = (tid & 15) * 8;
    const unsigned int* src = (const unsigned int*)&T[s_l][c8];
    unsigned int* d32 = (unsigned int*)(dst + (s0 + s_l) * CC + c8);
    d32[0] = src[0]; d32[1] = src[1]; d32[2] = src[2]; d32[3] = src[3];
}

// ---------------- Kernel 2: per-(p,g) MFMA + windowed max, LDS-staged B, 2-phase ----------------
__global__ __launch_bounds__(384) void score_kernel(
    const __hip_bfloat16* __restrict__ pf_t, const __hip_bfloat16* __restrict__ gf_t,
    const float* __restrict__ bn_g, const float* __restrict__ bn_b,
    const float* __restrict__ bn_m, const float* __restrict__ bn_v,
    const float* __restrict__ fc_w, const float* __restrict__ fc_b,
    const float* __restrict__ lbn_g, const float* __restrict__ lbn_b,
    const float* __restrict__ lbn_m, const float* __restrict__ lbn_v,
    float* __restrict__ out)
{
    // B staging: 2 buffers, chunk-major [16 q][16 row] x 16B => frag ks at byte ks*1024 + l*16
    __shared__ __align__(16) char bstage[2][4096];
    __shared__ unsigned short M1b[24 * M1LD];   // [hr][s]  max over wr, bf16
    __shared__ unsigned short M2b[HWSZ * M2LD]; // [r][hs]  max over ws, bf16
    __shared__ float red[6], wred[6];

    int bi = blockIdx.x;
    int p = bi >> 5, g = bi & 31;
    int tid = threadIdx.x, l = tid & 63, w = tid >> 6;   // w in 0..5

    const __hip_bfloat16* A = gf_t + (size_t)g * HWSZ * CC; // [r][c]
    const __hip_bfloat16* B = pf_t + (size_t)p * HWSZ * CC; // [s][c]

    int row_a = l & 15;
    int koff = (l >> 4) * 8;

    // stage B tile st into buf: waves 0-3 each stage a 1KB quarter.
    // LDS byte (w*1024 + i*16) <=> global element (st*16 + (i&15))*CC + (w*4 + (i>>4))*8
    #define STAGE_B(bufidx, st_)                                                         \
        if (w < 4) {                                                                     \
            const __hip_bfloat16* src = B + ((st_) * 16 + (l & 15)) * CC                 \
                                          + (w * 4 + (l >> 4)) * 8;                      \
            __builtin_amdgcn_global_load_lds(                                            \
                (const __attribute__((address_space(1))) void*)src,                      \
                (__attribute__((address_space(3))) void*)(&bstage[bufidx][w * 1024]),    \
                16, 0, 0);                                                               \
        }

    // prologue: stage st=0; A-frag register loads overlap the staging latency
    STAGE_B(0, 0)

    bf16x8 afr[2][4];
    #pragma unroll
    for (int rt = 0; rt < 2; ++rt) {
        const __hip_bfloat16* ap = A + (w * 32 + rt * 16 + row_a) * CC + koff;
        #pragma unroll
        for (int ks = 0; ks < 4; ++ks)
            afr[rt][ks] = *(const bf16x8*)(ap + ks * 32);
    }
    __syncthreads();   // st=0 staged

    for (int st = 0; st < 12; ++st) {
        int cur = st & 1;
        if (st < 11) { STAGE_B(cur ^ 1, st + 1) }   // issue next tile's DMA early

        const char* bb = bstage[cur];
        bf16x8 b0 = *(const bf16x8*)(bb + 0 * 1024 + l * 16);
        bf16x8 b1 = *(const bf16x8*)(bb + 1 * 1024 + l * 16);
        bf16x8 b2 = *(const bf16x8*)(bb + 2 * 1024 + l * 16);
        bf16x8 b3 = *(const bf16x8*)(bb + 3 * 1024 + l * 16);

        #pragma unroll
        for (int rt = 0; rt < 2; ++rt) {
            f32x4 acc = {0.f, 0.f, 0.f, 0.f};
            acc = __builtin_amdgcn_mfma_f32_16x16x32_bf16(afr[rt][0], b0, acc, 0, 0, 0);
            acc = __builtin_amdgcn_mfma_f32_16x16x32_bf16(afr[rt][1], b1, acc, 0, 0, 0);
            acc = __builtin_amdgcn_mfma_f32_16x16x32_bf16(afr[rt][2], b2, acc, 0, 0, 0);
            acc = __builtin_amdgcn_mfma_f32_16x16x32_bf16(afr[rt][3], b3, acc, 0, 0, 0);

            int RT = w * 2 + rt;
            // D layout: row = (l>>4)*4 + reg, col = l&15  (r = RT*16+row, s = st*16+col)

            // M1[hr][s]: max over the 8 wr rows in each hr group
            float mrow = fmaxf(fmaxf(acc[0], acc[1]), fmaxf(acc[2], acc[3]));
            mrow = fmaxf(mrow, __shfl_xor(mrow, 16));
            if (((l >> 4) & 1) == 0)
                M1b[(2 * RT + (l >> 5)) * M1LD + st * 16 + (l & 15)] = f2bf(mrow);

            // M2[r][hs]: max over 8 cols (ws) within each hs group
            float v0 = acc[0], v1 = acc[1], v2 = acc[2], v3 = acc[3];
            #pragma unroll
            for (int m = 1; m < 8; m <<= 1) {
                v0 = fmaxf(v0, __shfl_xor(v0, m));
                v1 = fmaxf(v1, __shfl_xor(v1, m));
                v2 = fmaxf(v2, __shfl_xor(v2, m));
                v3 = fmaxf(v3, __shfl_xor(v3, m));
            }
            if ((l & 7) == 0) {
                int hs = st * 2 + ((l >> 3) & 1);
                int rbase = RT * 16 + (l >> 4) * 4;
                M2b[(rbase + 0) * M2LD + hs] = f2bf(v0);
                M2b[(rbase + 1) * M2LD + hs] = f2bf(v1);
                M2b[(rbase + 2) * M2LD + hs] = f2bf(v2);
                M2b[(rbase + 3) * M2LD + hs] = f2bf(v3);
            }
        }
        // pipeline boundary: drains this wave's global_load_lds (next tile ready)
        // and guarantees all waves are done reading bstage[cur] before overwrite.
        __syncthreads();
    }

    // windowed max (6 consecutive h rows, start clip(h-3,0,18)) + fc_w-weighted sum
    float part = 0.f, wpart = 0.f;
    if (tid < HWSZ) {
        int h = tid >> 3;
        int st0 = h - 3; if (st0 < 0) st0 = 0; if (st0 > 18) st0 = 18;
        float v1 = -INFINITY, v2 = -INFINITY;
        #pragma unroll
        for (int i = 0; i < 6; ++i) {
            v1 = fmaxf(v1, bf2f(M1b[(st0 + i) * M1LD + tid]));
            v2 = fmaxf(v2, bf2f(M2b[tid * M2LD + st0 + i]));
        }
        float fw = fc_w[tid];
        part = fw * (v1 + v2);
        wpart = fw;
    }
    #pragma unroll
    for (int m = 1; m < 64; m <<= 1) {
        part  += __shfl_xor(part, m);
        wpart += __shfl_xor(wpart, m);
    }
    if (l == 0) { red[w] = part; wred[w] = wpart; }
    __syncthreads();

    if (tid == 0) {
        float total = red[0] + red[1] + red[2] + red[3] + red[4] + red[5];
        float Wsum  = wred[0] + wred[1] + wred[2] + wred[3] + wred[4] + wred[5];
        float k1 = bn_g[0] * rsqrtf(bn_v[0] + EPSV);
        float Y = k1 * total + 2.f * ((bn_b[0] - k1 * bn_m[0]) * Wsum + fc_b[0]);
        float kl = lbn_g[0] * rsqrtf(lbn_v[0] + EPSV);
        float Z = (Y - lbn_m[0]) * kl + lbn_b[0];
        out[bi] = 1.f / (1.f + expf(-Z));
    }
}

extern "C" void kernel_launch(void* const* d_in, const int* in_sizes, int n_in,
                              void* d_out, int out_size, void* d_ws, size_t ws_size,
                              hipStream_t stream)
{
    const float* prob  = (const float*)d_in[0];
    const float* gal   = (const float*)d_in[1];
    const float* se_w1 = (const float*)d_in[2];
    const float* se_w2 = (const float*)d_in[3];
    const float* sa_w  = (const float*)d_in[4];
    const float* sa_b  = (const float*)d_in[5];
    const float* bn_g  = (const float*)d_in[6];
    const float* bn_b  = (const float*)d_in[7];
    const float* bn_m  = (const float*)d_in[8];
    const float* bn_v  = (const float*)d_in[9];
    const float* fc_w  = (const float*)d_in[10];
    const float* fc_b  = (const float*)d_in[11];
    const float* lbn_g = (const float*)d_in[12];
    const float* lbn_b = (const float*)d_in[13];
    const float* lbn_m = (const float*)d_in[14];
    const float* lbn_v = (const float*)d_in[15];

    __hip_bfloat16* pf_t = (__hip_bfloat16*)d_ws;             // [32][192][128] bf16
    __hip_bfloat16* gf_t = pf_t + (size_t)32 * HWSZ * CC;     // [32][192][128] bf16
    float* ca_buf = (float*)(gf_t + (size_t)32 * HWSZ * CC);  // [64][128] f32
    float* sa_buf = ca_buf + 64 * CC;                         // [64][192] f32
    float* out = (float*)d_out;

    cbam_stats<<<64, 512, 0, stream>>>(prob, gal, se_w1, se_w2, sa_w, sa_b, ca_buf, sa_buf);
    cbam_apply<<<768, 256, 0, stream>>>(prob, gal, ca_buf, sa_buf, pf_t, gf_t);
    score_kernel<<<1024, 384, 0, stream>>>(pf_t, gf_t, bn_g, bn_b, bn_m, bn_v,
                                           fc_w, fc_b, lbn_g, lbn_b, lbn_m, lbn_v, out);
}

// Round 9
// 151.753 us; speedup vs baseline: 1.0147x; 1.0147x over previous
//
#include <hip/hip_runtime.h>
#include <hip/hip_bf16.h>

#define HH 24
#define WW 8
#define HWSZ 192
#define CC 128
#define EPSV 1e-5f

#define M1LD 200   // M1 [24][M1LD] bf16
#define M2LD 28    // M2 [192][M2LD] bf16

typedef __attribute__((ext_vector_type(8))) short bf16x8;
typedef __attribute__((ext_vector_type(4))) float f32x4;

__device__ __forceinline__ float sigmoidf_(float x) { return 1.0f / (1.0f + expf(-x)); }

__device__ __forceinline__ unsigned short f2bf(float f) {
    unsigned int u = __float_as_uint(f);
    unsigned int r = (u + 0x7fffu + ((u >> 16) & 1u)) >> 16;
    return (unsigned short)r;
}
__device__ __forceinline__ float bf2f(unsigned short s) {
    return __uint_as_float((unsigned int)s << 16);
}

// ---------------- Kernel 1a: CBAM stats (phases 1-5), 64 blocks x 512 ----------------
__global__ __launch_bounds__(512) void cbam_stats(
    const float* __restrict__ prob, const float* __restrict__ gal,
    const float* __restrict__ se_w1, const float* __restrict__ se_w2,
    const float* __restrict__ sa_w, const float* __restrict__ sa_b,
    float* __restrict__ ca_out, float* __restrict__ sa_out)
{
    __shared__ float mxs[CC], avs[CC], hid[16], cas[CC];
    __shared__ float smx2[2 * HWSZ], sav2[2 * HWSZ];
    __shared__ float wbuf[2 * 49 * 49];

    int n = blockIdx.x;
    const float* x = (n < 32) ? prob + (size_t)n * CC * HWSZ : gal + (size_t)(n - 32) * CC * HWSZ;

    int tid = threadIdx.x, l = tid & 63, w = tid >> 6;

    for (int i = tid; i < 2 * 49 * 49; i += 512) wbuf[i] = sa_w[i];

    // phase 1: per-channel max/mean over 192 spatial (8 waves x 16 channels)
    for (int i = 0; i < 16; ++i) {
        int c = w * 16 + i;
        const float* row = x + c * HWSZ;
        float a = row[l], b = row[l + 64], d = row[l + 128];
        float mv = fmaxf(a, fmaxf(b, d));
        float sv = a + b + d;
        #pragma unroll
        for (int m = 1; m < 64; m <<= 1) {
            mv = fmaxf(mv, __shfl_xor(mv, m));
            sv += __shfl_xor(sv, m);
        }
        if (l == 0) { mxs[c] = mv; avs[c] = sv * (1.0f / HWSZ); }
    }
    __syncthreads();

    // phase 2: hidden = relu(v @ W1^T); 16 outputs x 16 lanes x 8 channels
    if (tid < 256) {
        int j = tid >> 4, chunk = tid & 15;
        const float* v = (j < 8) ? mxs : avs;
        const float* wrow = se_w1 + (j & 7) * CC + chunk * 8;
        const float* vv = v + chunk * 8;
        float acc = 0.f;
        #pragma unroll
        for (int k = 0; k < 8; ++k) acc += vv[k] * wrow[k];
        #pragma unroll
        for (int m = 1; m < 16; m <<= 1) acc += __shfl_xor(acc, m);
        if (chunk == 0) hid[j] = fmaxf(acc, 0.f);
    }
    __syncthreads();

    // phase 3: ca[c]
    if (tid < CC) {
        float acc = 0.f;
        #pragma unroll
        for (int j = 0; j < 8; ++j) acc += (hid[j] + hid[8 + j]) * se_w2[tid * 8 + j];
        cas[tid] = sigmoidf_(acc);
        ca_out[n * CC + tid] = cas[tid];
    }
    __syncthreads();

    // phase 4: spatial max/sum over channels of out = x*ca (2 half-channel passes)
    if (tid < 2 * HWSZ) {
        int s = tid >> 1, half = tid & 1;
        int c0 = half * 64;
        float mv = -INFINITY, sv = 0.f;
        #pragma unroll 4
        for (int k = 0; k < 64; ++k) {
            float v = x[(c0 + k) * HWSZ + s] * cas[c0 + k];
            mv = fmaxf(mv, v); sv += v;
        }
        smx2[half * HWSZ + s] = mv; sav2[half * HWSZ + s] = sv;
    }
    __syncthreads();

    // phase 5: 49x49 conv (pad 24 = all-pairs) + sigmoid -> sa_out
    if (tid < HWSZ) {
        int y = tid >> 3, xx = tid & 7;
        float acc = sa_b[0];
        for (int iy = 0; iy < HH; ++iy) {
            int wy = iy - y + 24;
            const float* w0 = wbuf + wy * 49;
            const float* w1 = wbuf + 2401 + wy * 49;
            #pragma unroll
            for (int ix = 0; ix < WW; ++ix) {
                int wx = ix - xx + 24;
                int sp = iy * 8 + ix;
                float s0 = fmaxf(smx2[sp], smx2[HWSZ + sp]);
                float s1 = (sav2[sp] + sav2[HWSZ + sp]) * (1.0f / CC);
                acc += s0 * w0[wx] + s1 * w1[wx];
            }
        }
        sa_out[n * HWSZ + tid] = sigmoidf_(acc);
    }
}

// ---------------- Kernel 1b: CBAM apply + transpose, 768 blocks x 256 ----------------
__global__ __launch_bounds__(256) void cbam_apply(
    const float* __restrict__ prob, const float* __restrict__ gal,
    const float* __restrict__ ca_buf, const float* __restrict__ sa_buf,
    __hip_bfloat16* __restrict__ pf_t, __hip_bfloat16* __restrict__ gf_t)
{
    __shared__ unsigned short T[16][136];   // [s_local][c], padded
    __shared__ float sash[16];

    int n = blockIdx.x / 12;
    int s0 = (blockIdx.x % 12) * 16;
    const float* x = (n < 32) ? prob + (size_t)n * CC * HWSZ : gal + (size_t)(n - 32) * CC * HWSZ;
    __hip_bfloat16* dst = (n < 32) ? pf_t + (size_t)n * HWSZ * CC : gf_t + (size_t)(n - 32) * HWSZ * CC;

    int tid = threadIdx.x;
    if (tid < 16) sash[tid] = sa_buf[n * HWSZ + s0 + tid];
    __syncthreads();

    int c = tid >> 1, half = tid & 1;           // c: 0..127, half: 0..1
    float ca = ca_buf[n * CC + c];
    const float* xp = x + c * HWSZ + s0 + half * 8;
    float4 va = *(const float4*)xp;
    float4 vb = *(const float4*)(xp + 4);
    int r0 = half * 8;
    T[r0 + 0][c] = f2bf(va.x * (1.f + ca * sash[r0 + 0]));
    T[r0 + 1][c] = f2bf(va.y * (1.f + ca * sash[r0 + 1]));
    T[r0 + 2][c] = f2bf(va.z * (1.f + ca * sash[r0 + 2]));
    T[r0 + 3][c] = f2bf(va.w * (1.f + ca * sash[r0 + 3]));
    T[r0 + 4][c] = f2bf(vb.x * (1.f + ca * sash[r0 + 4]));
    T[r0 + 5][c] = f2bf(vb.y * (1.f + ca * sash[r0 + 5]));
    T[r0 + 6][c] = f2bf(vb.z * (1.f + ca * sash[r0 + 6]));
    T[r0 + 7][c] = f2bf(vb.w * (1.f + ca * sash[r0 + 7]));
    __syncthreads();

    int s_l = tid >> 4, c8 = (tid & 15) * 8;
    const unsigned int* src = (const unsigned int*)&T[s_l][c8];
    unsigned int* d32 = (unsigned int*)(dst + (s0 + s_l) * CC + c8);
    d32[0] = src[0]; d32[1] = src[1]; d32[2] = src[2]; d32[3] = src[3];
}

// ---------------- Kernel 2: full-B LDS, barrier-free loop, swapped-MFMA epilogue ----------------
__global__ __launch_bounds__(384) void score_kernel(
    const __hip_bfloat16* __restrict__ pf_t, const __hip_bfloat16* __restrict__ gf_t,
    const float* __restrict__ bn_g, const float* __restrict__ bn_b,
    const float* __restrict__ bn_m, const float* __restrict__ bn_v,
    const float* __restrict__ fc_w, const float* __restrict__ fc_b,
    const float* __restrict__ lbn_g, const float* __restrict__ lbn_b,
    const float* __restrict__ lbn_m, const float* __restrict__ lbn_v,
    float* __restrict__ out)
{
    // All 12 B-tiles staged once: [st][q][lane]x16B chunk-major (48 KB).
    __shared__ __align__(16) char Bs[12 * 4096];
    __shared__ unsigned short M1b[24 * M1LD];   // [hr][s]  max over wr, bf16
    __shared__ unsigned short M2b[HWSZ * M2LD]; // [r][hs]  max over ws, bf16
    __shared__ float red[6], wred[6];

    int bi = blockIdx.x;
    int p = bi >> 5, g = bi & 31;
    int tid = threadIdx.x, l = tid & 63, w = tid >> 6;   // w in 0..5

    const __hip_bfloat16* A = gf_t + (size_t)g * HWSZ * CC; // [r][c]
    const __hip_bfloat16* B = pf_t + (size_t)p * HWSZ * CC; // [s][c]

    // stage ALL of B: 48 wave-issues (1KB each), 8 per wave.
    // LDS byte (idx*1024 + i*16) <=> global element (st*16 + (i&15))*CC + (q*4 + (i>>4))*8
    #pragma unroll
    for (int i = 0; i < 8; ++i) {
        int idx = w * 8 + i;                 // 0..47 ; st = idx>>2, q = idx&3
        const __hip_bfloat16* src = B + ((idx >> 2) * 16 + (l & 15)) * CC
                                      + ((idx & 3) * 4 + (l >> 4)) * 8;
        __builtin_amdgcn_global_load_lds(
            (const __attribute__((address_space(1))) void*)src,
            (__attribute__((address_space(3))) void*)(&Bs[idx * 1024]),
            16, 0, 0);
    }

    // A fragments (register) overlap the staging latency
    int row_a = l & 15;
    int koff = (l >> 4) * 8;
    bf16x8 afr[2][4];
    #pragma unroll
    for (int rt = 0; rt < 2; ++rt) {
        const __hip_bfloat16* ap = A + (w * 32 + rt * 16 + row_a) * CC + koff;
        #pragma unroll
        for (int ks = 0; ks < 4; ++ks)
            afr[rt][ks] = *(const bf16x8*)(ap + ks * 32);
    }
    __syncthreads();   // staging complete; NO barriers from here to the final pass

    for (int st = 0; st < 12; ++st) {
        const char* bb = Bs + st * 4096;
        bf16x8 b0 = *(const bf16x8*)(bb + 0 * 1024 + l * 16);
        bf16x8 b1 = *(const bf16x8*)(bb + 1 * 1024 + l * 16);
        bf16x8 b2 = *(const bf16x8*)(bb + 2 * 1024 + l * 16);
        bf16x8 b3 = *(const bf16x8*)(bb + 3 * 1024 + l * 16);

        #pragma unroll
        for (int rt = 0; rt < 2; ++rt) {
            // D1[r][s] for M1, D2[s][r] (operand swap) for M2 — both reductions
            // become in-lane max over 4 regs + ONE shfl_xor(16).
            f32x4 acc1 = {0.f, 0.f, 0.f, 0.f};
            f32x4 acc2 = {0.f, 0.f, 0.f, 0.f};
            acc1 = __builtin_amdgcn_mfma_f32_16x16x32_bf16(afr[rt][0], b0, acc1, 0, 0, 0);
            acc2 = __builtin_amdgcn_mfma_f32_16x16x32_bf16(b0, afr[rt][0], acc2, 0, 0, 0);
            acc1 = __builtin_amdgcn_mfma_f32_16x16x32_bf16(afr[rt][1], b1, acc1, 0, 0, 0);
            acc2 = __builtin_amdgcn_mfma_f32_16x16x32_bf16(b1, afr[rt][1], acc2, 0, 0, 0);
            acc1 = __builtin_amdgcn_mfma_f32_16x16x32_bf16(afr[rt][2], b2, acc1, 0, 0, 0);
            acc2 = __builtin_amdgcn_mfma_f32_16x16x32_bf16(b2, afr[rt][2], acc2, 0, 0, 0);
            acc1 = __builtin_amdgcn_mfma_f32_16x16x32_bf16(afr[rt][3], b3, acc1, 0, 0, 0);
            acc2 = __builtin_amdgcn_mfma_f32_16x16x32_bf16(b3, afr[rt][3], acc2, 0, 0, 0);

            int RT = w * 2 + rt;

            // M1[hr][s]: D1 row=(l>>4)*4+reg (=r_sub), col=l&15 (=s_sub)
            float mrow = fmaxf(fmaxf(acc1[0], acc1[1]), fmaxf(acc1[2], acc1[3]));
            mrow = fmaxf(mrow, __shfl_xor(mrow, 16));
            if (((l >> 4) & 1) == 0)
                M1b[(2 * RT + (l >> 5)) * M1LD + st * 16 + (l & 15)] = f2bf(mrow);

            // M2[r][hs]: D2 row=(l>>4)*4+reg (=s_sub), col=l&15 (=r_sub)
            float mcol = fmaxf(fmaxf(acc2[0], acc2[1]), fmaxf(acc2[2], acc2[3]));
            mcol = fmaxf(mcol, __shfl_xor(mcol, 16));
            if (((l >> 4) & 1) == 0)
                M2b[(RT * 16 + (l & 15)) * M2LD + st * 2 + (l >> 5)] = f2bf(mcol);
        }
    }
    __syncthreads();

    // windowed max (6 consecutive h rows, start clip(h-3,0,18)) + fc_w-weighted sum
    float part = 0.f, wpart = 0.f;
    if (tid < HWSZ) {
        int h = tid >> 3;
        int st0 = h - 3; if (st0 < 0) st0 = 0; if (st0 > 18) st0 = 18;
        float v1 = -INFINITY, v2 = -INFINITY;
        #pragma unroll
        for (int i = 0; i < 6; ++i) {
            v1 = fmaxf(v1, bf2f(M1b[(st0 + i) * M1LD + tid]));
            v2 = fmaxf(v2, bf2f(M2b[tid * M2LD + st0 + i]));
        }
        float fw = fc_w[tid];
        part = fw * (v1 + v2);
        wpart = fw;
    }
    #pragma unroll
    for (int m = 1; m < 64; m <<= 1) {
        part  += __shfl_xor(part, m);
        wpart += __shfl_xor(wpart, m);
    }
    if (l == 0) { red[w] = part; wred[w] = wpart; }
    __syncthreads();

    if (tid == 0) {
        float total = red[0] + red[1] + red[2] + red[3] + red[4] + red[5];
        float Wsum  = wred[0] + wred[1] + wred[2] + wred[3] + wred[4] + wred[5];
        float k1 = bn_g[0] * rsqrtf(bn_v[0] + EPSV);
        float Y = k1 * total + 2.f * ((bn_b[0] - k1 * bn_m[0]) * Wsum + fc_b[0]);
        float kl = lbn_g[0] * rsqrtf(lbn_v[0] + EPSV);
        float Z = (Y - lbn_m[0]) * kl + lbn_b[0];
        out[bi] = 1.f / (1.f + expf(-Z));
    }
}

extern "C" void kernel_launch(void* const* d_in, const int* in_sizes, int n_in,
                              void* d_out, int out_size, void* d_ws, size_t ws_size,
                              hipStream_t stream)
{
    const float* prob  = (const float*)d_in[0];
    const float* gal   = (const float*)d_in[1];
    const float* se_w1 = (const float*)d_in[2];
    const float* se_w2 = (const float*)d_in[3];
    const float* sa_w  = (const float*)d_in[4];
    const float* sa_b  = (const float*)d_in[5];
    const float* bn_g  = (const float*)d_in[6];
    const float* bn_b  = (const float*)d_in[7];
    const float* bn_m  = (const float*)d_in[8];
    const float* bn_v  = (const float*)d_in[9];
    const float* fc_w  = (const float*)d_in[10];
    const float* fc_b  = (const float*)d_in[11];
    const float* lbn_g = (const float*)d_in[12];
    const float* lbn_b = (const float*)d_in[13];
    const float* lbn_m = (const float*)d_in[14];
    const float* lbn_v = (const float*)d_in[15];

    __hip_bfloat16* pf_t = (__hip_bfloat16*)d_ws;             // [32][192][128] bf16
    __hip_bfloat16* gf_t = pf_t + (size_t)32 * HWSZ * CC;     // [32][192][128] bf16
    float* ca_buf = (float*)(gf_t + (size_t)32 * HWSZ * CC);  // [64][128] f32
    float* sa_buf = ca_buf + 64 * CC;                         // [64][192] f32
    float* out = (float*)d_out;

    cbam_stats<<<64, 512, 0, stream>>>(prob, gal, se_w1, se_w2, sa_w, sa_b, ca_buf, sa_buf);
    cbam_apply<<<768, 256, 0, stream>>>(prob, gal, ca_buf, sa_buf, pf_t, gf_t);
    score_kernel<<<1024, 384, 0, stream>>>(pf_t, gf_t, bn_g, bn_b, bn_m, bn_v,
                                           fc_w, fc_b, lbn_g, lbn_b, lbn_m, lbn_v, out);
}